// Round 6
// baseline (110.862 us; speedup 1.0000x reference)
//
#include <hip/hip_runtime.h>
#include <hip/hip_fp16.h>

// MaddnessMatmul round 6: split encode/accumulate + software-pipelined encode.
//   out[m][n] = sum_c luts[c][enc(n,c)][m],  luts[c][k][m] = dot(B[m], P[c][k]).
//
// R5 post-mortem: kernels ~29us vs ~13.5us floor. Encode (single-wave blocks,
// one tile, no prefetch) convoys: all resident waves issue loads together then
// all wait vmcnt together; LDS/wave (16.6KB) caps encode at 8-9 waves/CU so
// stagger can't hide HBM latency. R6: encode = 2048 blocks (exactly 8/CU)
// x 2 tiles with register prefetch -- tile s+1's 16 float4 loads are in
// flight while tile s is scattered+encoded (34MB outstanding device-wide >>
// 6.3MB BW-delay product). Accum kernel unchanged (16 waves/CU, wave-capped).
//  - A tile row-major stride 65: gather bank (t+sd)%32 2-way = free.
//  - thresholds by LDS index (<=8 distinct addrs, broadcast) - no in-loop
//    scalar loads.
//  - f16 LUT, stride-24 entries; packed-f16 even/odd accumulators, f32
//    combine (absmax ~1 << 3.6 threshold).

#define NROWS 262144
#define DDIM  64
#define RSTR  65          // LDS floats per staged row (odd -> conflict-free)
#define LSTR  24          // LDS halfs per LUT entry (48B, b128 banks <=2-way)
#define EBLK  2048        // encode blocks (8/CU), x2 tiles x 64 rows = 262144
#define ETILES 2
#define ABLK  1024        // accum blocks: 1024 * 256 rows = 262144

typedef __attribute__((ext_vector_type(8))) _Float16 half8;
typedef __attribute__((ext_vector_type(4))) unsigned int u32x4;

__global__ __launch_bounds__(64) void encode_kernel(
    const float* __restrict__ A,      // [N][64]
    const float* __restrict__ B,      // [16][64]
    const float* __restrict__ P,      // [16][16][64]
    const int*   __restrict__ sd,     // [16][4]
    const float* __restrict__ sv,     // [16][4][8]
    _Float16* __restrict__ lutw,      // [256][16] f16 (d_ws)
    uint2* __restrict__ codes)        // [N] packed 16x4-bit (d_ws+8KB)
{
    __shared__ float rows_s[64 * RSTR];   // 16,640 B
    __shared__ float sv_s[512];           //  2,048 B
    const int t = threadIdx.x;

    // stage split_vals (512 floats = 128 float4; 2 per thread)
    ((float4*)sv_s)[t]      = ((const float4*)sv)[t];
    ((float4*)sv_s)[t + 64] = ((const float4*)sv)[t + 64];

    // prefetch tile 0 (64 rows = 1024 float4, 16/thread, coalesced)
    const float4* A4 = (const float4*)A;
    float4 R[16];
    {
        long base = (long)blockIdx.x * (64 * DDIM / 4);
        #pragma unroll
        for (int j = 0; j < 16; ++j) R[j] = A4[base + j * 64 + t];
    }

    // fused LUT build on first 16 blocks (independent; overlaps A-load wait)
    if (blockIdx.x < 16) {
        const int m = t & 15;
        const float4* Bp = (const float4*)(B + m * DDIM);
        float4 brow[16];
        #pragma unroll
        for (int q = 0; q < 16; ++q) brow[q] = Bp[q];
        #pragma unroll
        for (int i = 0; i < 4; ++i) {
            int o  = blockIdx.x * 256 + i * 64 + t;   // c*256 + k*16 + m
            int ck = o >> 4;
            const float4* Pp = (const float4*)(P + ck * DDIM);
            float dot = 0.f;
            #pragma unroll
            for (int q = 0; q < 16; ++q) {
                float4 p = Pp[q];
                dot += p.x * brow[q].x + p.y * brow[q].y
                     + p.z * brow[q].z + p.w * brow[q].w;
            }
            lutw[o] = (_Float16)dot;
        }
    }

    #pragma unroll
    for (int s = 0; s < ETILES; ++s) {
        const int tile = blockIdx.x + s * EBLK;

        __syncthreads();   // single wave: cheap waitcnt drain + barrier

        // scatter prefetched tile into LDS, row-major stride 65
        // bank (row + colq + jj) % 32 -> 2 lanes/bank = free
        #pragma unroll
        for (int j = 0; j < 16; ++j) {
            int f    = j * 64 + t;
            int row  = f >> 4;
            int colq = (f & 15) * 4;
            float* dst = &rows_s[row * RSTR + colq];
            dst[0] = R[j].x; dst[1] = R[j].y; dst[2] = R[j].z; dst[3] = R[j].w;
        }
        // issue next tile's loads NOW; in flight during encode below
        if (s + 1 < ETILES) {
            long base = (long)(tile + EBLK) * (64 * DDIM / 4);
            #pragma unroll
            for (int j = 0; j < 16; ++j) R[j] = A4[base + j * 64 + t];
        }

        __syncthreads();

        // encode row t: 16 codebooks x 4 levels; thresholds by LDS index
        const float* rrow = &rows_s[t * RSTR];
        unsigned int lo = 0, hi = 0;
        #pragma unroll
        for (int c = 0; c < 16; ++c) {
            const int sd0 = sd[c*4+0], sd1 = sd[c*4+1];
            const int sd2 = sd[c*4+2], sd3 = sd[c*4+3];
            float x0 = rrow[sd0];
            float x1 = rrow[sd1];
            float x2 = rrow[sd2];
            float x3 = rrow[sd3];
            int g = (x0 > sv_s[c*32]) ? 1 : 0;
            g = (g << 1) | ((x1 > sv_s[c*32 +  8 + g]) ? 1 : 0);
            g = (g << 1) | ((x2 > sv_s[c*32 + 16 + g]) ? 1 : 0);
            g = (g << 1) | ((x3 > sv_s[c*32 + 24 + g]) ? 1 : 0);
            if (c < 8) lo |= (unsigned)g << (4 * c);
            else       hi |= (unsigned)g << (4 * (c - 8));
        }
        codes[tile * 64 + t] = make_uint2(lo, hi);
    }
}

__global__ __launch_bounds__(256) void accum_kernel(
    const uint2* __restrict__ codes,  // [N]
    const _Float16* __restrict__ lutw,// [256][16] f16
    float* __restrict__ out)          // [16][N]
{
    __shared__ __align__(16) _Float16 lut_s[256 * LSTR];  // 12,288 B
    const int t = threadIdx.x;

    // stage LUT: one 32B entry per thread, padded stride 24 halfs
    {
        const u32x4* src = (const u32x4*)(lutw + t * 16);
        u32x4 q0 = src[0], q1 = src[1];
        *(u32x4*)(lut_s + t * LSTR)     = q0;
        *(u32x4*)(lut_s + t * LSTR + 8) = q1;
    }
    __syncthreads();

    const int n = blockIdx.x * 256 + t;
    const uint2 code = codes[n];

    half8 aE0 = {0,0,0,0,0,0,0,0}, aE1 = {0,0,0,0,0,0,0,0};
    half8 aO0 = {0,0,0,0,0,0,0,0}, aO1 = {0,0,0,0,0,0,0,0};

    #pragma unroll
    for (int c = 0; c < 8; ++c) {
        int g = (code.x >> (4 * c)) & 15;
        const _Float16* lp = lut_s + (c * 16 + g) * LSTR;
        half8 l0 = *(const half8*)(lp);
        half8 l1 = *(const half8*)(lp + 8);
        if (c & 1) { aO0 += l0; aO1 += l1; }
        else       { aE0 += l0; aE1 += l1; }
    }
    #pragma unroll
    for (int c = 8; c < 16; ++c) {
        int g = (code.y >> (4 * (c - 8))) & 15;
        const _Float16* lp = lut_s + (c * 16 + g) * LSTR;
        half8 l0 = *(const half8*)(lp);
        half8 l1 = *(const half8*)(lp + 8);
        if (c & 1) { aO0 += l0; aO1 += l1; }
        else       { aE0 += l0; aE1 += l1; }
    }

    #pragma unroll
    for (int m = 0; m < 8; ++m) {
        out[(long)m       * NROWS + n] = (float)aE0[m] + (float)aO0[m];
        out[(long)(m + 8) * NROWS + n] = (float)aE1[m] + (float)aO1[m];
    }
}

extern "C" void kernel_launch(void* const* d_in, const int* in_sizes, int n_in,
                              void* d_out, int out_size, void* d_ws, size_t ws_size,
                              hipStream_t stream) {
    const float* A  = (const float*)d_in[0];
    const float* B  = (const float*)d_in[1];
    const float* P  = (const float*)d_in[2];
    const int*   sd = (const int*)d_in[3];
    const float* sv = (const float*)d_in[4];
    float* out = (float*)d_out;

    _Float16* lutw  = (_Float16*)d_ws;                // 8 KB f16 LUT
    uint2*    codes = (uint2*)((char*)d_ws + 8192);   // 2 MB packed codes

    encode_kernel<<<dim3(EBLK), dim3(64), 0, stream>>>(A, B, P, sd, sv, lutw, codes);
    accum_kernel<<<dim3(ABLK), dim3(256), 0, stream>>>(codes, lutw, out);
}

// Round 7
// 110.164 us; speedup vs baseline: 1.0063x; 1.0063x over previous
//
#include <hip/hip_runtime.h>
#include <hip/hip_fp16.h>

// MaddnessMatmul round 7: kill the barrier vmcnt-drain in encode.
//   out[m][n] = sum_c luts[c][enc(n,c)][m],  luts[c][k][m] = dot(B[m], P[c][k]).
//
// R6 post-mortem: NEUTRAL. __syncthreads() compiles to s_waitcnt vmcnt(0)
// lgkmcnt(0) + s_barrier -> the tile s+1 prefetch is drained at the barrier
// before encode(s) runs; prefetch structurally defeated (same pathology as the
// m97 GEMM barrier drain). Encode blocks are SINGLE-WAVE, so __syncthreads is
// only an LDS-ordering fence: replace it with s_waitcnt lgkmcnt(0) (asm, with
// memory clobber). DS ops are in-order per wave, so write->read ordering holds
// and prefetched global loads stay in flight across the encode phase.
//  - encode: 2048 blocks (8 waves/CU) x 2 tiles x 64 rows; A tile row stride 65
//    (gather bank (t+sd)%32 2-way = free); thresholds by LDS index; LUT build
//    fused into blocks 0..15.
//  - accum: 512 blocks x 256 thr, 2 rows/thread (amortize 12KB LUT staging);
//    f16 LUT stride-24 entries, even/odd packed-f16 accumulators, f32 combine
//    (absmax ~1 << 3.6 threshold).

#define NROWS 262144
#define DDIM  64
#define RSTR  65          // LDS floats per staged row (odd -> conflict-free)
#define LSTR  24          // LDS halfs per LUT entry (48B, b128 banks <=2-way)
#define EBLK  2048        // encode blocks (8/CU), x2 tiles x 64 rows = 262144
#define ETILES 2
#define ABLK  512         // accum blocks: 512 * 512 rows = 262144

typedef __attribute__((ext_vector_type(8))) _Float16 half8;
typedef __attribute__((ext_vector_type(4))) unsigned int u32x4;

// single-wave LDS fence: orders ds_write -> ds_read without draining vmcnt
#define WAVE_LDS_FENCE() asm volatile("s_waitcnt lgkmcnt(0)" ::: "memory")

__global__ __launch_bounds__(64) void encode_kernel(
    const float* __restrict__ A,      // [N][64]
    const float* __restrict__ B,      // [16][64]
    const float* __restrict__ P,      // [16][16][64]
    const int*   __restrict__ sd,     // [16][4]
    const float* __restrict__ sv,     // [16][4][8]
    _Float16* __restrict__ lutw,      // [256][16] f16 (d_ws)
    uint2* __restrict__ codes)        // [N] packed 16x4-bit (d_ws+8KB)
{
    __shared__ float rows_s[64 * RSTR];   // 16,640 B
    __shared__ float sv_s[512];           //  2,048 B
    const int t = threadIdx.x;

    // stage split_vals (512 floats = 128 float4; 2 per thread)
    ((float4*)sv_s)[t]      = ((const float4*)sv)[t];
    ((float4*)sv_s)[t + 64] = ((const float4*)sv)[t + 64];

    // prefetch tile 0 (64 rows = 1024 float4, 16/thread, coalesced)
    const float4* A4 = (const float4*)A;
    float4 R[16];
    {
        long base = (long)blockIdx.x * (64 * DDIM / 4);
        #pragma unroll
        for (int j = 0; j < 16; ++j) R[j] = A4[base + j * 64 + t];
    }

    // fused LUT build on first 16 blocks (independent; overlaps A-load wait)
    if (blockIdx.x < 16) {
        const int m = t & 15;
        const float4* Bp = (const float4*)(B + m * DDIM);
        float4 brow[16];
        #pragma unroll
        for (int q = 0; q < 16; ++q) brow[q] = Bp[q];
        #pragma unroll
        for (int i = 0; i < 4; ++i) {
            int o  = blockIdx.x * 256 + i * 64 + t;   // c*256 + k*16 + m
            int ck = o >> 4;
            const float4* Pp = (const float4*)(P + ck * DDIM);
            float dot = 0.f;
            #pragma unroll
            for (int q = 0; q < 16; ++q) {
                float4 p = Pp[q];
                dot += p.x * brow[q].x + p.y * brow[q].y
                     + p.z * brow[q].z + p.w * brow[q].w;
            }
            lutw[o] = (_Float16)dot;
        }
    }

    #pragma unroll
    for (int s = 0; s < ETILES; ++s) {
        const int tile = blockIdx.x + s * EBLK;

        // scatter prefetched tile into LDS, row-major stride 65
        // (compiler staggers vmcnt waits per R[j]; DS in-order per wave keeps
        //  these writes behind the previous tile's reads)
        #pragma unroll
        for (int j = 0; j < 16; ++j) {
            int f    = j * 64 + t;
            int row  = f >> 4;
            int colq = (f & 15) * 4;
            float* dst = &rows_s[row * RSTR + colq];
            dst[0] = R[j].x; dst[1] = R[j].y; dst[2] = R[j].z; dst[3] = R[j].w;
        }
        // issue next tile's loads NOW; they stay in flight through encode
        if (s + 1 < ETILES) {
            long base = (long)(tile + EBLK) * (64 * DDIM / 4);
            #pragma unroll
            for (int j = 0; j < 16; ++j) R[j] = A4[base + j * 64 + t];
        }

        WAVE_LDS_FENCE();   // ds_write -> ds_read ordering; vmcnt untouched

        // encode row t: 16 codebooks x 4 levels; thresholds by LDS index
        const float* rrow = &rows_s[t * RSTR];
        unsigned int lo = 0, hi = 0;
        #pragma unroll
        for (int c = 0; c < 16; ++c) {
            const int sd0 = sd[c*4+0], sd1 = sd[c*4+1];
            const int sd2 = sd[c*4+2], sd3 = sd[c*4+3];
            float x0 = rrow[sd0];
            float x1 = rrow[sd1];
            float x2 = rrow[sd2];
            float x3 = rrow[sd3];
            int g = (x0 > sv_s[c*32]) ? 1 : 0;
            g = (g << 1) | ((x1 > sv_s[c*32 +  8 + g]) ? 1 : 0);
            g = (g << 1) | ((x2 > sv_s[c*32 + 16 + g]) ? 1 : 0);
            g = (g << 1) | ((x3 > sv_s[c*32 + 24 + g]) ? 1 : 0);
            if (c < 8) lo |= (unsigned)g << (4 * c);
            else       hi |= (unsigned)g << (4 * (c - 8));
        }
        codes[tile * 64 + t] = make_uint2(lo, hi);

        WAVE_LDS_FENCE();   // reads done before next tile's scatter (cheap)
    }
}

__global__ __launch_bounds__(256) void accum_kernel(
    const uint2* __restrict__ codes,  // [N]
    const _Float16* __restrict__ lutw,// [256][16] f16
    float* __restrict__ out)          // [16][N]
{
    __shared__ __align__(16) _Float16 lut_s[256 * LSTR];  // 12,288 B
    const int t = threadIdx.x;

    const int n0 = blockIdx.x * 512 + t;
    const int n1 = n0 + 256;
    // issue code loads before the barrier so they're in flight during staging
    const uint2 code0 = codes[n0];
    const uint2 code1 = codes[n1];

    // stage LUT: one 32B entry per thread, padded stride 24 halfs
    {
        const u32x4* src = (const u32x4*)(lutw + t * 16);
        u32x4 q0 = src[0], q1 = src[1];
        *(u32x4*)(lut_s + t * LSTR)     = q0;
        *(u32x4*)(lut_s + t * LSTR + 8) = q1;
    }
    __syncthreads();

    #pragma unroll
    for (int r = 0; r < 2; ++r) {
        const uint2 code = r ? code1 : code0;
        const int n = r ? n1 : n0;

        half8 aE0 = {0,0,0,0,0,0,0,0}, aE1 = {0,0,0,0,0,0,0,0};
        half8 aO0 = {0,0,0,0,0,0,0,0}, aO1 = {0,0,0,0,0,0,0,0};

        #pragma unroll
        for (int c = 0; c < 8; ++c) {
            int g = (code.x >> (4 * c)) & 15;
            const _Float16* lp = lut_s + (c * 16 + g) * LSTR;
            half8 l0 = *(const half8*)(lp);
            half8 l1 = *(const half8*)(lp + 8);
            if (c & 1) { aO0 += l0; aO1 += l1; }
            else       { aE0 += l0; aE1 += l1; }
        }
        #pragma unroll
        for (int c = 8; c < 16; ++c) {
            int g = (code.y >> (4 * (c - 8))) & 15;
            const _Float16* lp = lut_s + (c * 16 + g) * LSTR;
            half8 l0 = *(const half8*)(lp);
            half8 l1 = *(const half8*)(lp + 8);
            if (c & 1) { aO0 += l0; aO1 += l1; }
            else       { aE0 += l0; aE1 += l1; }
        }

        #pragma unroll
        for (int m = 0; m < 8; ++m) {
            out[(long)m       * NROWS + n] = (float)aE0[m] + (float)aO0[m];
            out[(long)(m + 8) * NROWS + n] = (float)aE1[m] + (float)aO1[m];
        }
    }
}

extern "C" void kernel_launch(void* const* d_in, const int* in_sizes, int n_in,
                              void* d_out, int out_size, void* d_ws, size_t ws_size,
                              hipStream_t stream) {
    const float* A  = (const float*)d_in[0];
    const float* B  = (const float*)d_in[1];
    const float* P  = (const float*)d_in[2];
    const int*   sd = (const int*)d_in[3];
    const float* sv = (const float*)d_in[4];
    float* out = (float*)d_out;

    _Float16* lutw  = (_Float16*)d_ws;                // 8 KB f16 LUT
    uint2*    codes = (uint2*)((char*)d_ws + 8192);   // 2 MB packed codes

    encode_kernel<<<dim3(EBLK), dim3(64), 0, stream>>>(A, B, P, sd, sv, lutw, codes);
    accum_kernel<<<dim3(ABLK), dim3(256), 0, stream>>>(codes, lutw, out);
}